// Round 8
// baseline (214.746 us; speedup 1.0000x reference)
//
#include <hip/hip_runtime.h>
#include <hip/hip_bf16.h>

// Problem shape (fixed by setup_inputs): B=8, Q=2048 -> N=16384 rows,
// D=1024, Dp=256, K=2048 prototypes.
#define N_ROWS 16384
#define DIM    1024
#define DP     256
#define NPROTO 2048

typedef float f32x4 __attribute__((ext_vector_type(4)));
typedef short s16x8 __attribute__((ext_vector_type(8)));
typedef short s16x4 __attribute__((ext_vector_type(4)));

__device__ __forceinline__ unsigned short f2bf(float f) {
  __hip_bfloat16 h = __float2bfloat16(f);   // RNE
  return __builtin_bit_cast(unsigned short, h);
}

// LDS-only barrier: waits for this wave's LDS ops, then syncs waves.
// Does NOT drain vmcnt -> global-load prefetches stay in flight across it
// (unlike __syncthreads, which emits s_waitcnt vmcnt(0)). Safe here: no
// cross-wave communication through GLOBAL memory inside the kernel.
__device__ __forceinline__ void lds_barrier() {
  asm volatile("s_waitcnt lgkmcnt(0)" ::: "memory");
  __builtin_amdgcn_s_barrier();
}

// ---- fused prep: projT[j][d]=bf16(proj[d][j]); Pb=bf16(P); pp=rowsum(P^2) ----
__global__ void k_prep(const float* __restrict__ proj,
                       const float* __restrict__ P,
                       unsigned short* __restrict__ projT,
                       unsigned short* __restrict__ Pb,
                       float* __restrict__ pp) {
  int b = blockIdx.x;
  if (b < (DIM * DP) / 256) {
    int t = b * 256 + threadIdx.x;          // t = j*1024 + d, coalesced writes
    int j = t >> 10;
    int d = t & 1023;
    projT[t] = f2bf(proj[(size_t)d * DP + j]);
  } else {
    int k = b - (DIM * DP) / 256;
    int d = threadIdx.x;                    // 256 threads = Dp
    float v = P[(size_t)k * DP + d];
    Pb[(size_t)k * DP + d] = f2bf(v);
    float s = v * v;
#pragma unroll
    for (int o = 1; o < 64; o <<= 1) s += __shfl_xor(s, o, 64);
    __shared__ float ws4[4];
    if ((threadIdx.x & 63) == 0) ws4[threadIdx.x >> 6] = s;
    __syncthreads();
    if (threadIdx.x == 0) pp[k] = ws4[0] + ws4[1] + ws4[2] + ws4[3];
  }
}

// ---- FUSED (R5 structure + LDS-only barriers + 2-deep named prefetch) ----
// Block = 32 rows, 256 threads = 4 waves, grid 512 -> 2 blocks/CU.
//   phase 1: Z[32][256] = normalize_rows((X - mean) @ proj) -> LDS (bf16)
//   phase 2: out[32][2048] = -sqrt(max(1 + pp - 2 * Z @ Pb^T, 0))
// LDS (59,008 B total):
//   [0     , 16896)  Zs   [32][264] bf16
//   [16896 , 17408)  rowsq[4][32]   f32
//   [17408 , 58880)  staging union, LD=36:
//        phase1: As[2][32][36] (4608) + Bs[2][256][36] (36864)
//        phase2: Ps[2][256][36] (36864)
__global__ __launch_bounds__(256, 2)
void k_fused(const float* __restrict__ X, const float* __restrict__ mean,
             const unsigned short* __restrict__ projT,
             const unsigned short* __restrict__ Pb,
             const float* __restrict__ pp, float* __restrict__ out) {
  __shared__ __align__(16) unsigned char smem[58880];
  auto Zs    = (unsigned short(*)[264])(smem);                    // [32][264]
  auto rowsq = (float(*)[32])(smem + 16896);                      // [4][32]
  auto As    = (unsigned short(*)[32][36])(smem + 17408);         // [2][32][36]
  auto Bs    = (unsigned short(*)[256][36])(smem + 22016);        // [2][256][36]
  auto Ps    = (unsigned short(*)[256][36])(smem + 17408);        // [2][256][36]

  const int tid  = threadIdx.x;
  const int lane = tid & 63;
  const int wv   = tid >> 6;        // wave id 0..3
  const int l15  = lane & 15;
  const int lhi  = lane >> 4;
  const int rb   = blockIdx.x * 32;

  // phase-1 staging coords:
  //  A: 32 rows x 32 f32 = 256 f32x4 chunks -> 1/thread
  //  B: 256 rows x 32 bf16 = 1024 s16x8 chunks -> 4/thread
  const int arow = tid >> 3;             // [0,32)
  const int ach4 = (tid & 7) * 4;
  const int brow = tid >> 2;             // [0,64), chunks at +0/64/128/192
  const int bch8 = (tid & 3) * 8;
  const float* xbase = X + (size_t)(rb + arow) * DIM + ach4;
  const float* mbase = mean + ach4;
  const unsigned short* pjbase = projT + (size_t)brow * DIM + bch8;

  // phase-2 staging coords: 256 rows x 32 bf16 = 1024 s16x8 -> 4/thread
  const int srow = tid >> 2;
  const int sch8 = (tid & 3) * 8;

  // ================= phase 1 =================
  f32x4 acc[2][4];
#pragma unroll
  for (int mf = 0; mf < 2; ++mf)
#pragma unroll
    for (int nf = 0; nf < 4; ++nf) acc[mf][nf] = (f32x4)0.0f;

  f32x4 xrA, mrA, xrB, mrB;
  s16x8 brA[4], brB[4];

#define P1_ISSUE(XR, MR, BR, KB)                                             \
  {                                                                          \
    XR = *(const f32x4*)(xbase + (KB));                                      \
    MR = *(const f32x4*)(mbase + (KB));                                      \
    _Pragma("unroll")                                                        \
    for (int i = 0; i < 4; ++i)                                              \
      BR[i] = *(const s16x8*)(pjbase + (size_t)i * 64 * DIM + (KB));         \
  }

#define P1_WRITE(CUR, XR, MR, BR)                                            \
  {                                                                          \
    f32x4 c = XR - MR;                                                       \
    s16x4 v;                                                                 \
    v[0] = (short)f2bf(c[0]); v[1] = (short)f2bf(c[1]);                      \
    v[2] = (short)f2bf(c[2]); v[3] = (short)f2bf(c[3]);                      \
    *(s16x4*)(&As[CUR][arow][ach4]) = v;                                     \
    _Pragma("unroll")                                                        \
    for (int i = 0; i < 4; ++i)                                              \
      *(s16x8*)(&Bs[CUR][brow + i * 64][bch8]) = BR[i];                      \
  }

#define P1_COMPUTE(CUR)                                                      \
  {                                                                          \
    int k0 = lhi * 8;                                                        \
    s16x8 a[2], b[4];                                                        \
    _Pragma("unroll")                                                        \
    for (int mf = 0; mf < 2; ++mf)                                           \
      a[mf] = *(const s16x8*)(&As[CUR][mf * 16 + l15][k0]);                  \
    _Pragma("unroll")                                                        \
    for (int nf = 0; nf < 4; ++nf)                                           \
      b[nf] = *(const s16x8*)(&Bs[CUR][wv * 64 + nf * 16 + l15][k0]);        \
    _Pragma("unroll")                                                        \
    for (int mf = 0; mf < 2; ++mf)                                           \
      _Pragma("unroll")                                                      \
      for (int nf = 0; nf < 4; ++nf)                                         \
        acc[mf][nf] = __builtin_amdgcn_mfma_f32_16x16x32_bf16(               \
            a[mf], b[nf], acc[mf][nf], 0, 0, 0);                             \
  }

  P1_ISSUE(xrA, mrA, brA, 0);
  P1_ISSUE(xrB, mrB, brB, 32);
  for (int t = 0; t < 32; t += 2) {
    P1_WRITE(0, xrA, mrA, brA);
    if (t + 2 < 32) P1_ISSUE(xrA, mrA, brA, (t + 2) * 32);
    lds_barrier();
    P1_COMPUTE(0);
    P1_WRITE(1, xrB, mrB, brB);
    if (t + 3 < 32) P1_ISSUE(xrB, mrB, brB, (t + 3) * 32);
    lds_barrier();
    P1_COMPUTE(1);
  }
#undef P1_ISSUE
#undef P1_WRITE
#undef P1_COMPUTE

  // phase-2 staging loads for steps 0,1 -- issued before the handoff;
  // lds_barrier does not drain them.
  s16x8 prA[4], prB[4];
#define P2_LOAD(REGS, S)                                                     \
  {                                                                          \
    const int ctl = (S) >> 3;                                                \
    const int kkl = ((S) & 7) * 32;                                          \
    _Pragma("unroll")                                                        \
    for (int i = 0; i < 4; ++i)                                              \
      REGS[i] = *(const s16x8*)(Pb +                                         \
          (size_t)(ctl * 256 + srow + i * 64) * DP + kkl + sch8);            \
  }
  P2_LOAD(prA, 0);
  P2_LOAD(prB, 1);

  // ---- handoff: row norms + normalized Z -> LDS ----
#pragma unroll
  for (int mf = 0; mf < 2; ++mf)
#pragma unroll
    for (int r = 0; r < 4; ++r) {
      float s = 0.0f;
#pragma unroll
      for (int nf = 0; nf < 4; ++nf) s += acc[mf][nf][r] * acc[mf][nf][r];
#pragma unroll
      for (int o = 1; o < 16; o <<= 1) s += __shfl_xor(s, o, 16);
      if (l15 == 0) rowsq[wv][mf * 16 + lhi * 4 + r] = s;
    }
  lds_barrier();
#pragma unroll
  for (int mf = 0; mf < 2; ++mf)
#pragma unroll
    for (int r = 0; r < 4; ++r) {
      int row  = mf * 16 + lhi * 4 + r;
      float n2 = rowsq[0][row] + rowsq[1][row] + rowsq[2][row] + rowsq[3][row];
      float inv = 1.0f / fmaxf(sqrtf(n2), 1e-12f);  // F.normalize eps
#pragma unroll
      for (int nf = 0; nf < 4; ++nf)
        Zs[row][wv * 64 + nf * 16 + l15] = f2bf(acc[mf][nf][r] * inv);
    }
  lds_barrier();

  // ================= phase 2 =================
  // 8 column-tiles of 256 protos; per tile K=256 in 8 steps of 32.
  // 2-deep prefetch (prA even steps, prB odd); one lds_barrier per step.
#define P2_WRITE(CUR, REGS)                                                  \
  {                                                                          \
    _Pragma("unroll")                                                        \
    for (int i = 0; i < 4; ++i)                                              \
      *(s16x8*)(&Ps[CUR][srow + i * 64][sch8]) = REGS[i];                    \
  }

#define P2_COMPUTE(CUR, KS)                                                  \
  {                                                                          \
    s16x8 a[2], b[4];                                                        \
    const int kz = (KS) * 32 + lhi * 8;                                      \
    const int k0 = lhi * 8;                                                  \
    _Pragma("unroll")                                                        \
    for (int mf = 0; mf < 2; ++mf)                                           \
      a[mf] = *(const s16x8*)(&Zs[mf * 16 + l15][kz]);                       \
    _Pragma("unroll")                                                        \
    for (int nf = 0; nf < 4; ++nf)                                           \
      b[nf] = *(const s16x8*)(&Ps[CUR][wv * 64 + nf * 16 + l15][k0]);        \
    _Pragma("unroll")                                                        \
    for (int mf = 0; mf < 2; ++mf)                                           \
      _Pragma("unroll")                                                      \
      for (int nf = 0; nf < 4; ++nf)                                         \
        acc2[mf][nf] = __builtin_amdgcn_mfma_f32_16x16x32_bf16(              \
            a[mf], b[nf], acc2[mf][nf], 0, 0, 0);                            \
  }

  for (int ct = 0; ct < 8; ++ct) {
    f32x4 acc2[2][4];
#pragma unroll
    for (int mf = 0; mf < 2; ++mf)
#pragma unroll
      for (int nf = 0; nf < 4; ++nf) acc2[mf][nf] = (f32x4)0.0f;

#pragma unroll
    for (int ks = 0; ks < 8; ks += 2) {
      const int s = ct * 8 + ks;
      P2_WRITE(0, prA);
      if (s + 2 < 64) P2_LOAD(prA, s + 2);
      lds_barrier();
      P2_COMPUTE(0, ks);
      P2_WRITE(1, prB);
      if (s + 3 < 64) P2_LOAD(prB, s + 3);
      lds_barrier();
      P2_COMPUTE(1, ks + 1);
    }

    // ---- epilogue for this column tile ----
    float ppv[4];
#pragma unroll
    for (int nf = 0; nf < 4; ++nf)
      ppv[nf] = pp[ct * 256 + wv * 64 + nf * 16 + l15];
#pragma unroll
    for (int mf = 0; mf < 2; ++mf)
#pragma unroll
      for (int r = 0; r < 4; ++r) {
        int row = rb + mf * 16 + lhi * 4 + r;
#pragma unroll
        for (int nf = 0; nf < 4; ++nf) {
          int col  = ct * 256 + wv * 64 + nf * 16 + l15;
          float d2 = fmaxf(1.0f + ppv[nf] - 2.0f * acc2[mf][nf][r], 0.0f);
          out[(size_t)row * NPROTO + col] = -sqrtf(d2);
        }
      }
  }
#undef P2_LOAD
#undef P2_WRITE
#undef P2_COMPUTE
}

extern "C" void kernel_launch(void* const* d_in, const int* in_sizes, int n_in,
                              void* d_out, int out_size, void* d_ws, size_t ws_size,
                              hipStream_t stream) {
  const float* X     = (const float*)d_in[0];  // [16384,1024]
  const float* mean  = (const float*)d_in[1];  // [1024]
  const float* proj  = (const float*)d_in[2];  // [1024,256]
  const float* proto = (const float*)d_in[3];  // [2048,256]
  float* out = (float*)d_out;                  // [16384,2048]

  char* ws = (char*)d_ws;
  // workspace layout (~1.5 MB total)
  size_t off = 0;
  unsigned short* projT = (unsigned short*)(ws + off); off += (size_t)DIM * DP * 2;    // 512 KB
  unsigned short* Pb    = (unsigned short*)(ws + off); off += (size_t)NPROTO * DP * 2; // 1 MB
  float* pp             = (float*)(ws + off);          off += (size_t)NPROTO * 4;      // 8 KB

  hipLaunchKernelGGL(k_prep, dim3((DIM * DP) / 256 + NPROTO), dim3(256), 0,
                     stream, proj, proto, projT, Pb, pp);
  hipLaunchKernelGGL(k_fused, dim3(N_ROWS / 32), dim3(256), 0, stream,
                     X, mean, projT, Pb, pp, out);
}

// Round 9
// 94.016 us; speedup vs baseline: 2.2841x; 2.2841x over previous
//
#include <hip/hip_runtime.h>
#include <hip/hip_bf16.h>

// Problem shape (fixed by setup_inputs): B=8, Q=2048 -> N=16384 rows,
// D=1024, Dp=256, K=2048 prototypes.
#define N_ROWS 16384
#define DIM    1024
#define DP     256
#define NPROTO 2048

typedef float f32x4 __attribute__((ext_vector_type(4)));
typedef short s16x8 __attribute__((ext_vector_type(8)));
typedef short s16x4 __attribute__((ext_vector_type(4)));

__device__ __forceinline__ unsigned short f2bf(float f) {
  __hip_bfloat16 h = __float2bfloat16(f);   // RNE
  return __builtin_bit_cast(unsigned short, h);
}

// ---- fused prep: projT[j][d]=bf16(proj[d][j]); Pb=bf16(P); pp=rowsum(P^2) ----
__global__ void k_prep(const float* __restrict__ proj,
                       const float* __restrict__ P,
                       unsigned short* __restrict__ projT,
                       unsigned short* __restrict__ Pb,
                       float* __restrict__ pp) {
  int b = blockIdx.x;
  if (b < (DIM * DP) / 256) {
    int t = b * 256 + threadIdx.x;          // t = j*1024 + d, coalesced writes
    int j = t >> 10;
    int d = t & 1023;
    projT[t] = f2bf(proj[(size_t)d * DP + j]);
  } else {
    int k = b - (DIM * DP) / 256;
    int d = threadIdx.x;                    // 256 threads = Dp
    float v = P[(size_t)k * DP + d];
    Pb[(size_t)k * DP + d] = f2bf(v);
    float s = v * v;
#pragma unroll
    for (int o = 1; o < 64; o <<= 1) s += __shfl_xor(s, o, 64);
    __shared__ float ws4[4];
    if ((threadIdx.x & 63) == 0) ws4[threadIdx.x >> 6] = s;
    __syncthreads();
    if (threadIdx.x == 0) pp[k] = ws4[0] + ws4[1] + ws4[2] + ws4[3];
  }
}

// ---- FUSED ----
// Block = 64 rows, 512 threads = 8 waves, grid 256 = 1 block/CU.
// Phase 1 (R5-proven staged pipeline, 32 barrier-steps):
//   Z[64][256] = normalize_rows((X - mean) @ proj) -> LDS (bf16).
// Phase 2 (NEW: zero barriers, zero LDS traffic in the loop):
//   wave (rg=wv&1, pg=wv>>1) owns rows rg*32..+32 / protos pg*512..+512.
//   A-fragments loaded ONCE from Zs into 64 VGPRs; B streamed directly
//   from L2-resident Pb with 2-deep named-register prefetch (brA/brB);
//   out = -sqrt(max(1 + pp - 2*s, 0)) streamed to HBM.
__global__ __launch_bounds__(512, 2)
void k_fused(const float* __restrict__ X, const float* __restrict__ mean,
             const unsigned short* __restrict__ projT,
             const unsigned short* __restrict__ Pb,
             const float* __restrict__ pp, float* __restrict__ out) {
  // LDS layout (87,296 B):
  //   [0     , 33792)  Zs   [64][264] bf16
  //   [33792 , 34048)  invs [64]      f32
  //   [34048 , 36096)  rowsq[8][64]   f32
  //   [36096 , 46336)  As   [2][64][40]
  //   [46336 , 87296)  Bs   [2][256][40]
  __shared__ __align__(16) unsigned char smem[87296];
  auto Zs    = (unsigned short(*)[264])(smem);
  auto invs  = (float*)(smem + 33792);
  auto rowsq = (float(*)[64])(smem + 34048);
  auto As    = (unsigned short(*)[64][40])(smem + 36096);
  auto Bs    = (unsigned short(*)[256][40])(smem + 46336);

  const int tid  = threadIdx.x;
  const int lane = tid & 63;
  const int wv   = tid >> 6;        // wave id 0..7
  const int l15  = lane & 15;
  const int lhi  = lane >> 4;
  const int rb   = blockIdx.x * 64;

  // phase-1 staging coords:
  //  A: 64 rows x 32 f32 = 512 f32x4 chunks -> 1/thread
  //  B: 256 rows x 32 bf16 = 1024 s16x8 chunks -> 2/thread
  const int arow = tid >> 3;
  const int ach4 = (tid & 7) * 4;
  const int brow = tid >> 2;             // [0,128), second chunk +128
  const int bch8 = (tid & 3) * 8;
  const float* xbase = X + (size_t)(rb + arow) * DIM + ach4;
  const float* mbase = mean + ach4;
  const unsigned short* pjbase = projT + (size_t)brow * DIM + bch8;

  // ================= phase 1 =================
  f32x4 acc[4][2];
#pragma unroll
  for (int mf = 0; mf < 4; ++mf)
#pragma unroll
    for (int nf = 0; nf < 2; ++nf) acc[mf][nf] = (f32x4)0.0f;

  f32x4 xr, mr;
  s16x8 b0r, b1r;

#define P1_ISSUE(KB)                                                         \
  {                                                                          \
    xr  = *(const f32x4*)(xbase + (KB));                                     \
    mr  = *(const f32x4*)(mbase + (KB));                                     \
    b0r = *(const s16x8*)(pjbase + (KB));                                    \
    b1r = *(const s16x8*)(pjbase + (size_t)128 * DIM + (KB));                \
  }

#define P1_WRITE(CUR)                                                        \
  {                                                                          \
    f32x4 c = xr - mr;                                                       \
    s16x4 v;                                                                 \
    v[0] = (short)f2bf(c[0]); v[1] = (short)f2bf(c[1]);                      \
    v[2] = (short)f2bf(c[2]); v[3] = (short)f2bf(c[3]);                      \
    *(s16x4*)(&As[CUR][arow][ach4])       = v;                               \
    *(s16x8*)(&Bs[CUR][brow][bch8])       = b0r;                             \
    *(s16x8*)(&Bs[CUR][brow + 128][bch8]) = b1r;                             \
  }

#define P1_COMPUTE(CUR)                                                      \
  {                                                                          \
    int k0 = lhi * 8;                                                        \
    s16x8 a[4], b[2];                                                        \
    _Pragma("unroll")                                                        \
    for (int mf = 0; mf < 4; ++mf)                                           \
      a[mf] = *(const s16x8*)(&As[CUR][mf * 16 + l15][k0]);                  \
    _Pragma("unroll")                                                        \
    for (int nf = 0; nf < 2; ++nf)                                           \
      b[nf] = *(const s16x8*)(&Bs[CUR][wv * 32 + nf * 16 + l15][k0]);        \
    _Pragma("unroll")                                                        \
    for (int mf = 0; mf < 4; ++mf)                                           \
      _Pragma("unroll")                                                      \
      for (int nf = 0; nf < 2; ++nf)                                         \
        acc[mf][nf] = __builtin_amdgcn_mfma_f32_16x16x32_bf16(               \
            a[mf], b[nf], acc[mf][nf], 0, 0, 0);                             \
  }

  P1_ISSUE(0);
#pragma unroll 2
  for (int t = 0; t < DIM / 32; ++t) {
    const int cur = t & 1;
    P1_WRITE(cur);
    if (t < DIM / 32 - 1) P1_ISSUE((t + 1) * 32);
    __syncthreads();
    P1_COMPUTE(cur);
  }
#undef P1_ISSUE
#undef P1_WRITE
#undef P1_COMPUTE

  // ---- handoff: row norms + normalized Z -> LDS ----
#pragma unroll
  for (int mf = 0; mf < 4; ++mf)
#pragma unroll
    for (int r = 0; r < 4; ++r) {
      float s = acc[mf][0][r] * acc[mf][0][r] + acc[mf][1][r] * acc[mf][1][r];
#pragma unroll
      for (int o = 1; o < 16; o <<= 1) s += __shfl_xor(s, o, 16);
      if (l15 == 0) rowsq[wv][mf * 16 + lhi * 4 + r] = s;
    }
  __syncthreads();
  if (tid < 64) {
    float n2 = 0.0f;
#pragma unroll
    for (int w = 0; w < 8; ++w) n2 += rowsq[w][tid];
    invs[tid] = 1.0f / fmaxf(sqrtf(n2), 1e-12f);  // F.normalize eps
  }
  __syncthreads();
#pragma unroll
  for (int mf = 0; mf < 4; ++mf)
#pragma unroll
    for (int r = 0; r < 4; ++r) {
      int row   = mf * 16 + lhi * 4 + r;
      float inv = invs[row];
#pragma unroll
      for (int nf = 0; nf < 2; ++nf)
        Zs[row][wv * 32 + nf * 16 + l15] = f2bf(acc[mf][nf][r] * inv);
    }
  __syncthreads();   // Zs complete; no further barriers in the kernel

  // ================= phase 2 (barrier-free, LDS-free loop) =================
  const int rg = wv & 1;    // row group:   rows  rg*32 .. +32
  const int pg = wv >> 1;   // proto group: cols  pg*512 .. +512

  // A-fragments once into registers: 2 mf x 8 ks = 16 frags (64 VGPR)
  s16x8 af[2][8];
#pragma unroll
  for (int mf = 0; mf < 2; ++mf)
#pragma unroll
    for (int ks = 0; ks < 8; ++ks)
      af[mf][ks] =
          *(const s16x8*)(&Zs[rg * 32 + mf * 16 + l15][ks * 32 + lhi * 8]);

  const unsigned short* pbb = Pb + ((size_t)pg * 512 + l15) * DP + lhi * 8;
  const float* ppb = pp + pg * 512;
  float* outb = out + (size_t)(rb + rg * 32) * NPROTO + pg * 512;

  // b-frag loads: 16 rows x 64B fully-consumed L2 lines per instruction.
  s16x8 brA[4], brB[4];
#define P2B(REGS, T)                                                         \
  {                                                                          \
    const int g_ = (T) >> 3, k_ = ((T) & 7) * 32;                            \
    _Pragma("unroll")                                                        \
    for (int nf = 0; nf < 4; ++nf)                                           \
      REGS[nf] = *(const s16x8*)(pbb + (size_t)(g_ * 64 + nf * 16) * DP + k_); \
  }

  P2B(brA, 0);
  P2B(brB, 1);
  for (int g = 0; g < 8; ++g) {        // 64-proto chunks of this wave's 512
    f32x4 acc2[2][4];
#pragma unroll
    for (int mf = 0; mf < 2; ++mf)
#pragma unroll
      for (int nf = 0; nf < 4; ++nf) acc2[mf][nf] = (f32x4)0.0f;

#pragma unroll
    for (int ks = 0; ks < 8; ks += 2) {
      const int t = g * 8 + ks;
#pragma unroll
      for (int mf = 0; mf < 2; ++mf)
#pragma unroll
        for (int nf = 0; nf < 4; ++nf)
          acc2[mf][nf] = __builtin_amdgcn_mfma_f32_16x16x32_bf16(
              af[mf][ks], brA[nf], acc2[mf][nf], 0, 0, 0);
      if (t + 2 < 64) P2B(brA, t + 2);
#pragma unroll
      for (int mf = 0; mf < 2; ++mf)
#pragma unroll
        for (int nf = 0; nf < 4; ++nf)
          acc2[mf][nf] = __builtin_amdgcn_mfma_f32_16x16x32_bf16(
              af[mf][ks + 1], brB[nf], acc2[mf][nf], 0, 0, 0);
      if (t + 3 < 64) P2B(brB, t + 3);
    }

    // ---- epilogue for this 64-proto chunk ----
    float ppv[4];
#pragma unroll
    for (int nf = 0; nf < 4; ++nf) ppv[nf] = ppb[g * 64 + nf * 16 + l15];
#pragma unroll
    for (int mf = 0; mf < 2; ++mf)
#pragma unroll
      for (int r = 0; r < 4; ++r) {
        const size_t rowoff = (size_t)(mf * 16 + lhi * 4 + r) * NPROTO;
#pragma unroll
        for (int nf = 0; nf < 4; ++nf) {
          float d2 = fmaxf(1.0f + ppv[nf] - 2.0f * acc2[mf][nf][r], 0.0f);
          outb[rowoff + g * 64 + nf * 16 + l15] = -sqrtf(d2);
        }
      }
  }
#undef P2B
}

extern "C" void kernel_launch(void* const* d_in, const int* in_sizes, int n_in,
                              void* d_out, int out_size, void* d_ws, size_t ws_size,
                              hipStream_t stream) {
  const float* X     = (const float*)d_in[0];  // [16384,1024]
  const float* mean  = (const float*)d_in[1];  // [1024]
  const float* proj  = (const float*)d_in[2];  // [1024,256]
  const float* proto = (const float*)d_in[3];  // [2048,256]
  float* out = (float*)d_out;                  // [16384,2048]

  char* ws = (char*)d_ws;
  // workspace layout (~1.5 MB total)
  size_t off = 0;
  unsigned short* projT = (unsigned short*)(ws + off); off += (size_t)DIM * DP * 2;    // 512 KB
  unsigned short* Pb    = (unsigned short*)(ws + off); off += (size_t)NPROTO * DP * 2; // 1 MB
  float* pp             = (float*)(ws + off);          off += (size_t)NPROTO * 4;      // 8 KB

  hipLaunchKernelGGL(k_prep, dim3((DIM * DP) / 256 + NPROTO), dim3(256), 0,
                     stream, proj, proto, projT, Pb, pp);
  hipLaunchKernelGGL(k_fused, dim3(N_ROWS / 64), dim3(512), 0, stream,
                     X, mean, projT, Pb, pp, out);
}

// Round 10
// 63.626 us; speedup vs baseline: 3.3751x; 1.4776x over previous
//
#include <hip/hip_runtime.h>
#include <hip/hip_bf16.h>

// Problem shape (fixed by setup_inputs): B=8, Q=2048 -> N=16384 rows,
// D=1024, Dp=256, K=2048 prototypes.
#define N_ROWS 16384
#define DIM    1024
#define DP     256
#define NPROTO 2048

typedef float f32x4 __attribute__((ext_vector_type(4)));
typedef short s16x8 __attribute__((ext_vector_type(8)));

__device__ __forceinline__ unsigned short f2bf(float f) {
  __hip_bfloat16 h = __float2bfloat16(f);   // RNE
  return __builtin_bit_cast(unsigned short, h);
}

// LDS-only barrier (no vmcnt drain; global prefetches stay in flight).
__device__ __forceinline__ void lds_barrier() {
  asm volatile("s_waitcnt lgkmcnt(0)" ::: "memory");
  __builtin_amdgcn_s_barrier();
}

// ---- prep: build FRAGMENT-ORDER operands ----
// projT_sw[cg][kb][lane][8]: cg in [0,16) 16-col groups of proj-output,
//   kb in [0,32) 32-wide K chunks; lane's 8 bf16 = proj[kb*32+(lane>>4)*8+j][cg*16+(lane&15)].
// Pb_sw[pgrp][kb][lane][8]: pgrp in [0,128) 16-proto groups, kb in [0,8);
//   lane's 8 bf16 = proto[pgrp*16+(lane&15)][kb*32+(lane>>4)*8+j].
// A wave's MFMA B-fragment load is then base + lane*16B: one coalesced 1KB read.
__global__ void k_prep(const float* __restrict__ proj,
                       const float* __restrict__ P,
                       unsigned short* __restrict__ projT_sw,
                       unsigned short* __restrict__ Pb_sw,
                       float* __restrict__ pp) {
  int b = blockIdx.x;
  int t = threadIdx.x;
  if (b < 128) {                      // projT_sw: 32768 16B chunks
    int q    = b * 256 + t;
    int lane = q & 63, kb = (q >> 6) & 31, cg = q >> 11;
    int c  = cg * 16 + (lane & 15);
    int k0 = kb * 32 + (lane >> 4) * 8;
    s16x8 v;
#pragma unroll
    for (int j = 0; j < 8; ++j)
      v[j] = (short)f2bf(proj[(size_t)(k0 + j) * DP + c]);
    *(s16x8*)(projT_sw + (size_t)q * 8) = v;
  } else if (b < 384) {               // Pb_sw: 65536 16B chunks
    int q    = (b - 128) * 256 + t;
    int lane = q & 63, kb = (q >> 6) & 7, pg = q >> 9;
    const float* src = P + (size_t)(pg * 16 + (lane & 15)) * DP +
                       kb * 32 + (lane >> 4) * 8;
    s16x8 v;
#pragma unroll
    for (int j = 0; j < 8; ++j) v[j] = (short)f2bf(src[j]);
    *(s16x8*)(Pb_sw + (size_t)q * 8) = v;
  } else {                            // pp: one block per proto
    int k = b - 384;
    float v = P[(size_t)k * DP + t];
    float s = v * v;
#pragma unroll
    for (int o = 1; o < 64; o <<= 1) s += __shfl_xor(s, o, 64);
    __shared__ float ws4[4];
    if ((t & 63) == 0) ws4[t >> 6] = s;
    __syncthreads();
    if (t == 0) pp[k] = ws4[0] + ws4[1] + ws4[2] + ws4[3];
  }
}

// ---- FUSED: 64 rows/block, 512 threads = 8 waves, grid 256 = 1/CU ----
// Phase 1 (16 steps, BK=64, lds_barrier only): A (X-tile) staged via LDS
//   with 2-deep reg prefetch; B reg-direct coalesced from projT_sw.
// Handoff: row-norms, normalized Z -> Zs (3 barriers).
// Phase 2 (ZERO barriers, zero LDS traffic): wave (rg=wv&1,pg=wv>>1) owns
//   rows rg*32..+32, protos pg*512..+512; A-frags once in 64 VGPR from Zs;
//   B coalesced 2-deep from Pb_sw; -sqrt epilogue streams to out.
__global__ __launch_bounds__(512, 2)
void k_fused(const float* __restrict__ X, const float* __restrict__ mean,
             const unsigned short* __restrict__ projT_sw,
             const unsigned short* __restrict__ Pb_sw,
             const float* __restrict__ pp, float* __restrict__ out) {
  __shared__ __align__(16) unsigned short Zs[64][264];   // 33792 B
  __shared__ __align__(16) unsigned short As[2][64][72]; // 18432 B
  __shared__ __align__(16) float mean_s[DIM];            //  4096 B
  __shared__ float rowsq[8][64];                         //  2048 B
  __shared__ float invs[64];                             //   256 B

  const int tid  = threadIdx.x;
  const int lane = tid & 63;
  const int wv   = tid >> 6;        // wave id 0..7
  const int l15  = lane & 15;
  const int lhi  = lane >> 4;
  const int rb   = blockIdx.x * 64;

  // stage mean once
  if (tid < 256)
    *(f32x4*)&mean_s[tid * 4] = *(const f32x4*)(mean + tid * 4);
  __syncthreads();

  // phase-1 staging coords: thread stages row tid>>3, cols (tid&7)*8 (+t*64)
  const int arow = tid >> 3;
  const int ach  = (tid & 7) * 8;
  const float* xbase = X + (size_t)(rb + arow) * DIM + ach;
  // phase-1 B base: wave wv covers col-groups 2wv, 2wv+1
  const unsigned short* pj_base =
      projT_sw + (size_t)(wv * 2) * 32 * 64 * 8 + (size_t)lane * 8;

  f32x4 acc[4][2];
#pragma unroll
  for (int mf = 0; mf < 4; ++mf)
#pragma unroll
    for (int cg = 0; cg < 2; ++cg) acc[mf][cg] = (f32x4)0.0f;

  f32x4 x0A, x1A, x0B, x1B;
  s16x8 bfA[4], bfB[4];   // [cgi*2+kk]

#define P1X(X0, X1, T)                                                       \
  {                                                                          \
    X0 = *(const f32x4*)(xbase + (T) * 64);                                  \
    X1 = *(const f32x4*)(xbase + (T) * 64 + 4);                              \
  }
#define P1B(REGS, T)                                                         \
  {                                                                          \
    _Pragma("unroll")                                                        \
    for (int cgi = 0; cgi < 2; ++cgi)                                        \
      _Pragma("unroll")                                                      \
      for (int kk = 0; kk < 2; ++kk)                                         \
        REGS[cgi * 2 + kk] = *(const s16x8*)(pj_base +                       \
            (size_t)(cgi * 32 + (T) * 2 + kk) * 512);                        \
  }
#define P1W(CUR, X0, X1, T)                                                  \
  {                                                                          \
    const float* mp = &mean_s[(T) * 64 + ach];                               \
    f32x4 m0 = *(const f32x4*)mp;                                            \
    f32x4 m1 = *(const f32x4*)(mp + 4);                                      \
    f32x4 c0 = X0 - m0, c1 = X1 - m1;                                        \
    s16x8 v;                                                                 \
    v[0] = (short)f2bf(c0[0]); v[1] = (short)f2bf(c0[1]);                    \
    v[2] = (short)f2bf(c0[2]); v[3] = (short)f2bf(c0[3]);                    \
    v[4] = (short)f2bf(c1[0]); v[5] = (short)f2bf(c1[1]);                    \
    v[6] = (short)f2bf(c1[2]); v[7] = (short)f2bf(c1[3]);                    \
    *(s16x8*)(&As[CUR][arow][ach]) = v;                                      \
  }
#define P1C(CUR, BF)                                                         \
  {                                                                          \
    s16x8 a[4][2];                                                           \
    _Pragma("unroll")                                                        \
    for (int mf = 0; mf < 4; ++mf)                                           \
      _Pragma("unroll")                                                      \
      for (int kk = 0; kk < 2; ++kk)                                         \
        a[mf][kk] = *(const s16x8*)(&As[CUR][mf * 16 + l15][kk * 32 + lhi * 8]); \
    _Pragma("unroll")                                                        \
    for (int mf = 0; mf < 4; ++mf)                                           \
      _Pragma("unroll")                                                      \
      for (int cgi = 0; cgi < 2; ++cgi)                                      \
        _Pragma("unroll")                                                    \
        for (int kk = 0; kk < 2; ++kk)                                       \
          acc[mf][cgi] = __builtin_amdgcn_mfma_f32_16x16x32_bf16(            \
              a[mf][kk], BF[cgi * 2 + kk], acc[mf][cgi], 0, 0, 0);           \
  }

  P1X(x0A, x1A, 0); P1B(bfA, 0);
  P1X(x0B, x1B, 1); P1B(bfB, 1);
  for (int t = 0; t < 16; t += 2) {
    P1W(0, x0A, x1A, t);
    if (t + 2 < 16) P1X(x0A, x1A, t + 2);
    lds_barrier();
    P1C(0, bfA);
    if (t + 2 < 16) P1B(bfA, t + 2);
    P1W(1, x0B, x1B, t + 1);
    if (t + 3 < 16) P1X(x0B, x1B, t + 3);
    lds_barrier();
    P1C(1, bfB);
    if (t + 3 < 16) P1B(bfB, t + 3);
  }
#undef P1X
#undef P1B
#undef P1W
#undef P1C

  // issue phase-2 first B loads now (survive the handoff barriers)
  const int rg = wv & 1;    // rows  rg*32 .. +32
  const int pg = wv >> 1;   // protos pg*512 .. +512
  const unsigned short* pb_base =
      Pb_sw + (size_t)(pg * 32) * 8 * 64 * 8 + (size_t)lane * 8;
  s16x8 brA[4], brB[4];
#define P2B(REGS, T)                                                         \
  {                                                                          \
    const int g_ = (T) >> 3, k_ = (T) & 7;                                   \
    _Pragma("unroll")                                                        \
    for (int nf = 0; nf < 4; ++nf)                                           \
      REGS[nf] = *(const s16x8*)(pb_base +                                   \
          (size_t)((g_ * 4 + nf) * 8 + k_) * 512);                           \
  }
  P2B(brA, 0);
  P2B(brB, 1);

  // ---- handoff: row norms + normalized Z -> Zs ----
#pragma unroll
  for (int mf = 0; mf < 4; ++mf)
#pragma unroll
    for (int r = 0; r < 4; ++r) {
      float s = acc[mf][0][r] * acc[mf][0][r] + acc[mf][1][r] * acc[mf][1][r];
#pragma unroll
      for (int o = 1; o < 16; o <<= 1) s += __shfl_xor(s, o, 16);
      if (l15 == 0) rowsq[wv][mf * 16 + lhi * 4 + r] = s;
    }
  lds_barrier();
  if (tid < 64) {
    float n2 = 0.0f;
#pragma unroll
    for (int w = 0; w < 8; ++w) n2 += rowsq[w][tid];
    invs[tid] = 1.0f / fmaxf(sqrtf(n2), 1e-12f);  // F.normalize eps
  }
  lds_barrier();
#pragma unroll
  for (int mf = 0; mf < 4; ++mf)
#pragma unroll
    for (int r = 0; r < 4; ++r) {
      int row   = mf * 16 + lhi * 4 + r;
      float inv = invs[row];
#pragma unroll
      for (int cgi = 0; cgi < 2; ++cgi)
        Zs[row][wv * 32 + cgi * 16 + l15] = f2bf(acc[mf][cgi][r] * inv);
    }
  lds_barrier();

  // ================= phase 2 (no barriers, no LDS traffic) ===============
  s16x8 af[2][8];
#pragma unroll
  for (int mf = 0; mf < 2; ++mf)
#pragma unroll
    for (int ks = 0; ks < 8; ++ks)
      af[mf][ks] =
          *(const s16x8*)(&Zs[rg * 32 + mf * 16 + l15][ks * 32 + lhi * 8]);

  const float* ppb = pp + pg * 512;
  float* outb = out + (size_t)(rb + rg * 32) * NPROTO + pg * 512;

  for (int g = 0; g < 8; ++g) {        // 64-proto chunks of this wave's 512
    f32x4 acc2[2][4];
#pragma unroll
    for (int mf = 0; mf < 2; ++mf)
#pragma unroll
      for (int nf = 0; nf < 4; ++nf) acc2[mf][nf] = (f32x4)0.0f;

#pragma unroll
    for (int ks = 0; ks < 8; ks += 2) {
      const int t = g * 8 + ks;
#pragma unroll
      for (int mf = 0; mf < 2; ++mf)
#pragma unroll
        for (int nf = 0; nf < 4; ++nf)
          acc2[mf][nf] = __builtin_amdgcn_mfma_f32_16x16x32_bf16(
              af[mf][ks], brA[nf], acc2[mf][nf], 0, 0, 0);
      if (t + 2 < 64) P2B(brA, t + 2);
#pragma unroll
      for (int mf = 0; mf < 2; ++mf)
#pragma unroll
        for (int nf = 0; nf < 4; ++nf)
          acc2[mf][nf] = __builtin_amdgcn_mfma_f32_16x16x32_bf16(
              af[mf][ks + 1], brB[nf], acc2[mf][nf], 0, 0, 0);
      if (t + 3 < 64) P2B(brB, t + 3);
    }

    // ---- epilogue for this 64-proto chunk ----
    float ppv[4];
#pragma unroll
    for (int nf = 0; nf < 4; ++nf) ppv[nf] = ppb[g * 64 + nf * 16 + l15];
#pragma unroll
    for (int mf = 0; mf < 2; ++mf)
#pragma unroll
      for (int r = 0; r < 4; ++r) {
        const size_t rowoff = (size_t)(mf * 16 + lhi * 4 + r) * NPROTO;
#pragma unroll
        for (int nf = 0; nf < 4; ++nf) {
          float d2 = fmaxf(1.0f + ppv[nf] - 2.0f * acc2[mf][nf][r], 0.0f);
          outb[rowoff + g * 64 + nf * 16 + l15] = -sqrtf(d2);
        }
      }
  }
#undef P2B
}

extern "C" void kernel_launch(void* const* d_in, const int* in_sizes, int n_in,
                              void* d_out, int out_size, void* d_ws, size_t ws_size,
                              hipStream_t stream) {
  const float* X     = (const float*)d_in[0];  // [16384,1024]
  const float* mean  = (const float*)d_in[1];  // [1024]
  const float* proj  = (const float*)d_in[2];  // [1024,256]
  const float* proto = (const float*)d_in[3];  // [2048,256]
  float* out = (float*)d_out;                  // [16384,2048]

  char* ws = (char*)d_ws;
  // workspace layout (~1.5 MB total)
  size_t off = 0;
  unsigned short* projT_sw = (unsigned short*)(ws + off); off += (size_t)DIM * DP * 2;    // 512 KB
  unsigned short* Pb_sw    = (unsigned short*)(ws + off); off += (size_t)NPROTO * DP * 2; // 1 MB
  float* pp                = (float*)(ws + off);          off += (size_t)NPROTO * 4;      // 8 KB

  hipLaunchKernelGGL(k_prep, dim3(384 + NPROTO), dim3(256), 0, stream,
                     proj, proto, projT_sw, Pb_sw, pp);
  hipLaunchKernelGGL(k_fused, dim3(N_ROWS / 64), dim3(512), 0, stream,
                     X, mean, projT_sw, Pb_sw, pp, out);
}

// Round 11
// 60.073 us; speedup vs baseline: 3.5747x; 1.0591x over previous
//
#include <hip/hip_runtime.h>
#include <hip/hip_bf16.h>

// Problem shape (fixed by setup_inputs): B=8, Q=2048 -> N=16384 rows,
// D=1024, Dp=256, K=2048 prototypes.
#define N_ROWS 16384
#define DIM    1024
#define DP     256
#define NPROTO 2048

typedef float f32x4 __attribute__((ext_vector_type(4)));
typedef short s16x8 __attribute__((ext_vector_type(8)));
typedef short s16x4 __attribute__((ext_vector_type(4)));

__device__ __forceinline__ unsigned short f2bf(float f) {
  __hip_bfloat16 h = __float2bfloat16(f);   // RNE
  return __builtin_bit_cast(unsigned short, h);
}

// LDS-only barrier (no vmcnt drain; global prefetches stay in flight).
__device__ __forceinline__ void lds_barrier() {
  asm volatile("s_waitcnt lgkmcnt(0)" ::: "memory");
  __builtin_amdgcn_s_barrier();
}

// ---- prep: build FRAGMENT-ORDER operands ----
// projT_sw[cg][kb][lane][8]: cg in [0,16) 16-col groups of proj-output,
//   kb in [0,32) 32-wide K chunks; lane's 8 bf16 = proj[kb*32+(lane>>4)*8+j][cg*16+(lane&15)].
// Pb_sw[pgrp][kb][lane][8]: pgrp in [0,128) 16-proto groups, kb in [0,8);
//   lane's 8 bf16 = proto[pgrp*16+(lane&15)][kb*32+(lane>>4)*8+j].
// A wave's MFMA B-fragment load is then base + lane*16B: one coalesced 1KB read.
__global__ void k_prep(const float* __restrict__ proj,
                       const float* __restrict__ P,
                       unsigned short* __restrict__ projT_sw,
                       unsigned short* __restrict__ Pb_sw,
                       float* __restrict__ pp) {
  int b = blockIdx.x;
  int t = threadIdx.x;
  if (b < 128) {                      // projT_sw: 32768 16B chunks
    int q    = b * 256 + t;
    int lane = q & 63, kb = (q >> 6) & 31, cg = q >> 11;
    int c  = cg * 16 + (lane & 15);
    int k0 = kb * 32 + (lane >> 4) * 8;
    s16x8 v;
#pragma unroll
    for (int j = 0; j < 8; ++j)
      v[j] = (short)f2bf(proj[(size_t)(k0 + j) * DP + c]);
    *(s16x8*)(projT_sw + (size_t)q * 8) = v;
  } else if (b < 384) {               // Pb_sw: 65536 16B chunks
    int q    = (b - 128) * 256 + t;
    int lane = q & 63, kb = (q >> 6) & 7, pg = q >> 9;
    const float* src = P + (size_t)(pg * 16 + (lane & 15)) * DP +
                       kb * 32 + (lane >> 4) * 8;
    s16x8 v;
#pragma unroll
    for (int j = 0; j < 8; ++j) v[j] = (short)f2bf(src[j]);
    *(s16x8*)(Pb_sw + (size_t)q * 8) = v;
  } else {                            // pp: one block per proto
    int k = b - 384;
    float v = P[(size_t)k * DP + t];
    float s = v * v;
#pragma unroll
    for (int o = 1; o < 64; o <<= 1) s += __shfl_xor(s, o, 64);
    __shared__ float ws4[4];
    if ((t & 63) == 0) ws4[t >> 6] = s;
    __syncthreads();
    if (t == 0) pp[k] = ws4[0] + ws4[1] + ws4[2] + ws4[3];
  }
}

// ---- FUSED: 32 rows/block, 512 threads = 8 waves, grid 512 -> 2 blocks/CU ----
// Phase 1 (16 steps, BK=64, lds_barrier only): A (X-tile) staged via LDS
//   with 2-deep reg prefetch; B reg-direct coalesced from projT_sw.
// Handoff: row-norms, normalized Z -> Zs (3 lds_barriers).
// Phase 2 (ZERO barriers): each wave owns ALL 32 rows x protos wv*256..+256
//   (row-independent B reads -> minimal L2 traffic, 1 MB/block);
//   A-frags re-read per-ks from LDS-resident Zs (keeps VGPR <= 128 so two
//   blocks stay resident); B coalesced 2-deep from Pb_sw; -sqrt streamed.
__global__ __launch_bounds__(512, 4)
void k_fused(const float* __restrict__ X, const float* __restrict__ mean,
             const unsigned short* __restrict__ projT_sw,
             const unsigned short* __restrict__ Pb_sw,
             const float* __restrict__ pp, float* __restrict__ out) {
  __shared__ __align__(16) unsigned short Zs[32][264];   // 16896 B
  __shared__ __align__(16) unsigned short As[2][32][72]; //  9216 B
  __shared__ __align__(16) float mean_s[DIM];            //  4096 B
  __shared__ float rowsq[8][32];                         //  1024 B
  __shared__ float invs[32];                             //   128 B

  const int tid  = threadIdx.x;
  const int lane = tid & 63;
  const int wv   = tid >> 6;        // wave id 0..7
  const int l15  = lane & 15;
  const int lhi  = lane >> 4;
  const int rb   = blockIdx.x * 32;

  // stage mean once
  if (tid < 256)
    *(f32x4*)&mean_s[tid * 4] = *(const f32x4*)(mean + tid * 4);
  __syncthreads();

  // phase-1 staging coords: thread stages row tid>>4, cols (tid&15)*4 (+t*64)
  const int arow = tid >> 4;             // [0,32)
  const int ach  = (tid & 15) * 4;
  const float* xbase = X + (size_t)(rb + arow) * DIM + ach;
  // phase-1 B base: wave wv covers col-groups 2wv, 2wv+1
  const unsigned short* pj_base =
      projT_sw + (size_t)(wv * 2) * 32 * 64 * 8 + (size_t)lane * 8;

  f32x4 acc[2][2];
#pragma unroll
  for (int mf = 0; mf < 2; ++mf)
#pragma unroll
    for (int cg = 0; cg < 2; ++cg) acc[mf][cg] = (f32x4)0.0f;

  f32x4 xA, xB;
  s16x8 bfA[4], bfB[4];   // [cgi*2+kk]

#define P1X(XR, T) { XR = *(const f32x4*)(xbase + (T) * 64); }
#define P1B(REGS, T)                                                         \
  {                                                                          \
    _Pragma("unroll")                                                        \
    for (int cgi = 0; cgi < 2; ++cgi)                                        \
      _Pragma("unroll")                                                      \
      for (int kk = 0; kk < 2; ++kk)                                         \
        REGS[cgi * 2 + kk] = *(const s16x8*)(pj_base +                       \
            (size_t)(cgi * 32 + (T) * 2 + kk) * 512);                        \
  }
#define P1W(CUR, XR, T)                                                      \
  {                                                                          \
    f32x4 m0 = *(const f32x4*)&mean_s[(T) * 64 + ach];                       \
    f32x4 c0 = XR - m0;                                                      \
    s16x4 v;                                                                 \
    v[0] = (short)f2bf(c0[0]); v[1] = (short)f2bf(c0[1]);                    \
    v[2] = (short)f2bf(c0[2]); v[3] = (short)f2bf(c0[3]);                    \
    *(s16x4*)(&As[CUR][arow][ach]) = v;                                      \
  }
#define P1C(CUR, BF)                                                         \
  {                                                                          \
    s16x8 a[2][2];                                                           \
    _Pragma("unroll")                                                        \
    for (int mf = 0; mf < 2; ++mf)                                           \
      _Pragma("unroll")                                                      \
      for (int kk = 0; kk < 2; ++kk)                                         \
        a[mf][kk] = *(const s16x8*)(&As[CUR][mf * 16 + l15][kk * 32 + lhi * 8]); \
    _Pragma("unroll")                                                        \
    for (int mf = 0; mf < 2; ++mf)                                           \
      _Pragma("unroll")                                                      \
      for (int cgi = 0; cgi < 2; ++cgi)                                      \
        _Pragma("unroll")                                                    \
        for (int kk = 0; kk < 2; ++kk)                                       \
          acc[mf][cgi] = __builtin_amdgcn_mfma_f32_16x16x32_bf16(            \
              a[mf][kk], BF[cgi * 2 + kk], acc[mf][cgi], 0, 0, 0);           \
  }

  P1X(xA, 0); P1B(bfA, 0);
  P1X(xB, 1); P1B(bfB, 1);
  for (int t = 0; t < 16; t += 2) {
    P1W(0, xA, t);
    if (t + 2 < 16) P1X(xA, t + 2);
    lds_barrier();
    P1C(0, bfA);
    if (t + 2 < 16) P1B(bfA, t + 2);
    P1W(1, xB, t + 1);
    if (t + 3 < 16) P1X(xB, t + 3);
    lds_barrier();
    P1C(1, bfB);
    if (t + 3 < 16) P1B(bfB, t + 3);
  }
#undef P1X
#undef P1B
#undef P1W
#undef P1C

  // issue phase-2 first B loads now (survive the handoff barriers).
  // wave wv owns protos wv*256..+256 = proto-groups wv*16..+16.
  const unsigned short* pb_base =
      Pb_sw + (size_t)(wv * 16) * 8 * 64 * 8 + (size_t)lane * 8;
  s16x8 brA[4], brB[4];
#define P2B(REGS, T)                                                         \
  {                                                                          \
    const int g_ = (T) >> 3, k_ = (T) & 7;                                   \
    _Pragma("unroll")                                                        \
    for (int nf = 0; nf < 4; ++nf)                                           \
      REGS[nf] = *(const s16x8*)(pb_base +                                   \
          (size_t)((g_ * 4 + nf) * 8 + k_) * 512);                           \
  }
  P2B(brA, 0);
  P2B(brB, 1);

  // ---- handoff: row norms + normalized Z -> Zs ----
#pragma unroll
  for (int mf = 0; mf < 2; ++mf)
#pragma unroll
    for (int r = 0; r < 4; ++r) {
      float s = acc[mf][0][r] * acc[mf][0][r] + acc[mf][1][r] * acc[mf][1][r];
#pragma unroll
      for (int o = 1; o < 16; o <<= 1) s += __shfl_xor(s, o, 16);
      if (l15 == 0) rowsq[wv][mf * 16 + lhi * 4 + r] = s;
    }
  lds_barrier();
  if (tid < 32) {
    float n2 = 0.0f;
#pragma unroll
    for (int w = 0; w < 8; ++w) n2 += rowsq[w][tid];
    invs[tid] = 1.0f / fmaxf(sqrtf(n2), 1e-12f);  // F.normalize eps
  }
  lds_barrier();
#pragma unroll
  for (int mf = 0; mf < 2; ++mf)
#pragma unroll
    for (int r = 0; r < 4; ++r) {
      int row   = mf * 16 + lhi * 4 + r;
      float inv = invs[row];
#pragma unroll
      for (int cgi = 0; cgi < 2; ++cgi)
        Zs[row][wv * 32 + cgi * 16 + l15] = f2bf(acc[mf][cgi][r] * inv);
    }
  lds_barrier();

  // ================= phase 2 (no barriers) =================
  const float* ppb = pp + wv * 256;
  float* outb = out + (size_t)rb * NPROTO + wv * 256;

  for (int g = 0; g < 4; ++g) {        // 64-proto chunks of this wave's 256
    f32x4 acc2[2][4];
#pragma unroll
    for (int mf = 0; mf < 2; ++mf)
#pragma unroll
      for (int nf = 0; nf < 4; ++nf) acc2[mf][nf] = (f32x4)0.0f;

#pragma unroll
    for (int ks = 0; ks < 8; ks += 2) {
      const int t = g * 8 + ks;
      {
        s16x8 a0 = *(const s16x8*)(&Zs[l15][ks * 32 + lhi * 8]);
        s16x8 a1 = *(const s16x8*)(&Zs[16 + l15][ks * 32 + lhi * 8]);
#pragma unroll
        for (int nf = 0; nf < 4; ++nf) {
          acc2[0][nf] = __builtin_amdgcn_mfma_f32_16x16x32_bf16(
              a0, brA[nf], acc2[0][nf], 0, 0, 0);
          acc2[1][nf] = __builtin_amdgcn_mfma_f32_16x16x32_bf16(
              a1, brA[nf], acc2[1][nf], 0, 0, 0);
        }
      }
      if (t + 2 < 32) P2B(brA, t + 2);
      {
        s16x8 a0 = *(const s16x8*)(&Zs[l15][(ks + 1) * 32 + lhi * 8]);
        s16x8 a1 = *(const s16x8*)(&Zs[16 + l15][(ks + 1) * 32 + lhi * 8]);
#pragma unroll
        for (int nf = 0; nf < 4; ++nf) {
          acc2[0][nf] = __builtin_amdgcn_mfma_f32_16x16x32_bf16(
              a0, brB[nf], acc2[0][nf], 0, 0, 0);
          acc2[1][nf] = __builtin_amdgcn_mfma_f32_16x16x32_bf16(
              a1, brB[nf], acc2[1][nf], 0, 0, 0);
        }
      }
      if (t + 3 < 32) P2B(brB, t + 3);
    }

    // ---- epilogue for this 64-proto chunk ----
    float ppv[4];
#pragma unroll
    for (int nf = 0; nf < 4; ++nf) ppv[nf] = ppb[g * 64 + nf * 16 + l15];
#pragma unroll
    for (int mf = 0; mf < 2; ++mf)
#pragma unroll
      for (int r = 0; r < 4; ++r) {
        const size_t rowoff = (size_t)(mf * 16 + lhi * 4 + r) * NPROTO;
#pragma unroll
        for (int nf = 0; nf < 4; ++nf) {
          float d2 = fmaxf(1.0f + ppv[nf] - 2.0f * acc2[mf][nf][r], 0.0f);
          outb[rowoff + g * 64 + nf * 16 + l15] = -sqrtf(d2);
        }
      }
  }
#undef P2B
}

extern "C" void kernel_launch(void* const* d_in, const int* in_sizes, int n_in,
                              void* d_out, int out_size, void* d_ws, size_t ws_size,
                              hipStream_t stream) {
  const float* X     = (const float*)d_in[0];  // [16384,1024]
  const float* mean  = (const float*)d_in[1];  // [1024]
  const float* proj  = (const float*)d_in[2];  // [1024,256]
  const float* proto = (const float*)d_in[3];  // [2048,256]
  float* out = (float*)d_out;                  // [16384,2048]

  char* ws = (char*)d_ws;
  // workspace layout (~1.5 MB total)
  size_t off = 0;
  unsigned short* projT_sw = (unsigned short*)(ws + off); off += (size_t)DIM * DP * 2;    // 512 KB
  unsigned short* Pb_sw    = (unsigned short*)(ws + off); off += (size_t)NPROTO * DP * 2; // 1 MB
  float* pp                = (float*)(ws + off);          off += (size_t)NPROTO * 4;      // 8 KB

  hipLaunchKernelGGL(k_prep, dim3(384 + NPROTO), dim3(256), 0, stream,
                     proj, proto, projT_sw, Pb_sw, pp);
  hipLaunchKernelGGL(k_fused, dim3(N_ROWS / 32), dim3(512), 0, stream,
                     X, mean, projT_sw, Pb_sw, pp, out);
}